// Round 13
// baseline (579.921 us; speedup 1.0000x reference)
//
#include <hip/hip_runtime.h>

typedef __attribute__((ext_vector_type(8))) short short8v;
typedef __attribute__((ext_vector_type(4))) short short4v;
typedef __attribute__((ext_vector_type(4))) float float4v;
typedef __attribute__((ext_vector_type(2))) unsigned int uint2v;

#define MFMA16(a,b,c) __builtin_amdgcn_mfma_f32_16x16x32_bf16(a,b,c,0,0,0)

__device__ __forceinline__ unsigned short f2b(float f) {
    union { float f; unsigned u; } v; v.f = f;
    unsigned r = v.u + 0x7FFFu + ((v.u >> 16) & 1u);
    return (unsigned short)(r >> 16);
}
__device__ __forceinline__ float b2f(unsigned short s) {
    union { unsigned u; float f; } v; v.u = ((unsigned)s) << 16;
    return v.f;
}
// RNE f32x8 -> bf16x8 via v_cvt_pk_bf16_f32 (same rounding as f2b)
__device__ __forceinline__ short8v pack8(float4v a, float4v b) {
    union { unsigned u[4]; short8v s; } o;
    asm("v_cvt_pk_bf16_f32 %0, %1, %2" : "=v"(o.u[0]) : "v"(a[0]), "v"(a[1]));
    asm("v_cvt_pk_bf16_f32 %0, %1, %2" : "=v"(o.u[1]) : "v"(a[2]), "v"(a[3]));
    asm("v_cvt_pk_bf16_f32 %0, %1, %2" : "=v"(o.u[2]) : "v"(b[0]), "v"(b[1]));
    asm("v_cvt_pk_bf16_f32 %0, %1, %2" : "=v"(o.u[3]) : "v"(b[2]), "v"(b[3]));
    return o.s;
}

// ---------------------------------------------------------------------------
// P1: consolidated f32 -> bf16 pack for hidden / Wq / Wk / Wv (one launch).
// ---------------------------------------------------------------------------
__global__ __launch_bounds__(256) void pack_all(
    const float* __restrict__ hidden, const float* __restrict__ Wq,
    const float* __restrict__ Wk, const float* __restrict__ Wv,
    unsigned short* __restrict__ hb, unsigned short* __restrict__ Wqb,
    unsigned short* __restrict__ Wkb, unsigned short* __restrict__ Wvb) {
    const int bid = blockIdx.x;
    const float* in; unsigned short* out; int i;
    if (bid < 2048)      { in = hidden; out = hb;  i = bid * 256 + threadIdx.x; }
    else if (bid < 2560) { in = Wq; out = Wqb; i = (bid - 2048) * 256 + threadIdx.x; }
    else if (bid < 3072) { in = Wk; out = Wkb; i = (bid - 2560) * 256 + threadIdx.x; }
    else                 { in = Wv; out = Wvb; i = (bid - 3072) * 256 + threadIdx.x; }
    float4v a = *(const float4v*)&in[(size_t)i * 8];
    float4v b = *(const float4v*)&in[(size_t)i * 8 + 4];
    *(short8v*)&out[(size_t)i * 8] = pack8(a, b);
}

// ---------------------------------------------------------------------------
// P2 (FUSED): one launch for q, k, v.
// ---------------------------------------------------------------------------
__global__ __launch_bounds__(256) void qkv_gemm(
    const unsigned short* __restrict__ A,     // [4096][1024] bf16
    const unsigned short* __restrict__ Wqb, const unsigned short* __restrict__ Wkb,
    const unsigned short* __restrict__ Wvb,   // each [1024][1024] bf16 [n][k]
    const float* __restrict__ bq, const float* __restrict__ bk,
    const float* __restrict__ bv,
    unsigned short* __restrict__ outq) {      // qh | kh | vT consecutive 4M each
    const int n0g = blockIdx.x * 64;
    const int which = n0g >> 10;
    const int n0 = n0g & 1023;
    const unsigned short* W = (which == 0) ? Wqb : (which == 1) ? Wkb : Wvb;
    const float* bias = (which == 0) ? bq : (which == 1) ? bk : bv;
    unsigned short* out = outq + (size_t)which * 4194304;
    const int vmode = (which == 2);
    const int wave = threadIdx.x >> 6, lane = threadIdx.x & 63;
    const int m0 = blockIdx.y * 128 + wave * 32;
    const int lrow = lane & 15, g8 = (lane >> 4) << 3, row4 = (lane >> 4) << 2;
    float4v acc[2][4] = {};
    const unsigned short* Ap = A + (size_t)(m0 + lrow) * 1024 + g8;
    const unsigned short* Wp = W + (size_t)(n0 + lrow) * 1024 + g8;
#pragma unroll 2
    for (int k0 = 0; k0 < 1024; k0 += 32) {
        short8v a0 = *(const short8v*)(Ap + k0);
        short8v a1 = *(const short8v*)(Ap + 16 * 1024 + k0);
        short8v b0 = *(const short8v*)(Wp + k0);
        short8v b1 = *(const short8v*)(Wp + 16 * 1024 + k0);
        short8v b2 = *(const short8v*)(Wp + 32 * 1024 + k0);
        short8v b3 = *(const short8v*)(Wp + 48 * 1024 + k0);
        acc[0][0] = MFMA16(a0, b0, acc[0][0]); acc[0][1] = MFMA16(a0, b1, acc[0][1]);
        acc[0][2] = MFMA16(a0, b2, acc[0][2]); acc[0][3] = MFMA16(a0, b3, acc[0][3]);
        acc[1][0] = MFMA16(a1, b0, acc[1][0]); acc[1][1] = MFMA16(a1, b1, acc[1][1]);
        acc[1][2] = MFMA16(a1, b2, acc[1][2]); acc[1][3] = MFMA16(a1, b3, acc[1][3]);
    }
#pragma unroll
    for (int nt = 0; nt < 4; ++nt) {
        const int n = n0 + nt * 16 + lrow;           // C col = lane&15
        const float bz = bias[n];
        const int h = n >> 6, d = n & 63;
#pragma unroll
        for (int mt = 0; mt < 2; ++mt) {
            const int mb = m0 + mt * 16 + row4;      // C row = (lane>>4)*4 + j
            if (vmode == 0) {
#pragma unroll
                for (int j = 0; j < 4; ++j) {
                    const int m = mb + j;
                    const int b = m >> 10, l = m & 1023;
                    out[(((size_t)(b * 16 + h) << 10) + l) * 64 + d] = f2b(acc[mt][nt][j] + bz);
                }
            } else {
                const int b = mb >> 10, r = mb & 1023;
                short4v pk;
#pragma unroll
                for (int j = 0; j < 4; ++j) pk[j] = (short)f2b(acc[mt][nt][j] + bz);
                *(short4v*)&out[((((size_t)(b * 16 + h)) << 6) + d) * 1024 + r] = pk;
            }
        }
    }
}

// ---------------------------------------------------------------------------
// P3: headproj
// ---------------------------------------------------------------------------
__global__ __launch_bounds__(256) void headproj(
    const unsigned short* __restrict__ xh,  // [64][1024][64] bf16
    const float* __restrict__ Wsx,          // [64][64] f32
    const float* __restrict__ bsx,          // [64]
    unsigned short* __restrict__ x2b,       // [1024][64][64] bf16
    float* __restrict__ xbv) {              // [1024][64]
    __shared__ __align__(16) float Ws[64 * 64];
    __shared__ float bs[64];
    __shared__ __align__(16) unsigned short Xl[64 * 64];
    const int tid = threadIdx.x;
    const int l = blockIdx.x;
#pragma unroll
    for (int i = 0; i < 4; ++i)
        *(float4v*)&Ws[tid * 4 + i * 1024] = *(const float4v*)&Wsx[tid * 4 + i * 1024];
    if (tid < 64) bs[tid] = bsx[tid];
    {
        const int bhh = tid >> 2, dq = (tid & 3) * 16;
        const unsigned short* src = &xh[((size_t)bhh * 1024 + l) * 64 + dq];
        *(short8v*)&Xl[bhh * 64 + dq] = *(const short8v*)src;
        *(short8v*)&Xl[bhh * 64 + dq + 8] = *(const short8v*)(src + 8);
    }
    __syncthreads();
    const int bh = tid >> 2, e0 = (tid & 3) * 16;
    float acc[16] = {};
    float bacc = 0.f;
    for (int d = 0; d < 64; ++d) {
        const float xd = b2f(Xl[bh * 64 + d]);
        bacc += xd * bs[d];
        const float* wr = &Ws[d * 64 + e0];
#pragma unroll
        for (int e = 0; e < 16; e += 4) {
            float4v w = *(const float4v*)&wr[e];
            acc[e] += xd * w[0]; acc[e + 1] += xd * w[1];
            acc[e + 2] += xd * w[2]; acc[e + 3] += xd * w[3];
        }
    }
    short8v p0, p1;
#pragma unroll
    for (int e = 0; e < 8; ++e) { p0[e] = (short)f2b(acc[e]); p1[e] = (short)f2b(acc[e + 8]); }
    unsigned short* dst = &x2b[((size_t)l * 64 + bh) * 64 + e0];
    *(short8v*)dst = p0; *(short8v*)(dst + 8) = p1;
    if ((tid & 3) == 0) xbv[l * 64 + bh] = bacc;
}

// ---------------------------------------------------------------------------
// P4 v11: 32l x 16r tile (halves k2 re-read traffic: l-blocks 64 -> 32).
// 4 waves = (l-half lh, bh-half bhh); two bh-group passes per wave, each
// reusing the verified c3 -> t3g-JIT -> T2 pipeline. S staged in two 16-l
// phases (keys congruent mod 8 with the verified 16x16 pattern).
// LDS 72 KB -> 2 blocks/CU. Grid (64 r-tiles, 32 l-tiles).
// ---------------------------------------------------------------------------
__global__ __launch_bounds__(256, 2) void struct_fused(
    const float* __restrict__ S,              // [1024][1024][64] f32
    const unsigned short* __restrict__ q2b,   // [1024][64][64] bf16
    const unsigned short* __restrict__ k2b,   // [1024][64][64] bf16
    const float* __restrict__ qbv,            // [1024][64]
    const float* __restrict__ kbv,            // [1024][64]
    unsigned short* __restrict__ sb) {        // [1024][64][1024] bf16
    __shared__ __align__(16) unsigned short Ssh[512 * 64];       // 64 KB, row = l*16+r
    __shared__ __align__(16) unsigned short t3g[4][4][16][16];   // 8 KB
    const int tid = threadIdx.x;
    const int w = tid >> 6, lane = tid & 63;
    const int lrow = lane & 15, g = lane >> 4;
    const int g8 = g << 3, row4 = g << 2;
    const int lh = w >> 1, bhh = w & 1;
    const int r0 = blockIdx.x << 4, l0 = blockIdx.y << 5;

    // ---- stage S (32 l x 16 r) in two 16-l phases, swizzled bf16 ----
#pragma unroll
    for (int ph = 0; ph < 2; ++ph) {
        const int u = tid & 15, roff = tid >> 4;
        const float* gp = S + ((size_t)(l0 + ph * 16) * 1024 + r0 + roff) * 64 + u * 4;
        float4v f[16];
#pragma unroll
        for (int i = 0; i < 16; ++i)
            f[i] = *(const float4v*)(gp + (size_t)i * 65536);
#pragma unroll
        for (int i = 0; i < 16; ++i) {
            const int R = ph * 256 + (i << 4) + roff;   // = l*16 + r
            const int K3 = (roff ^ i) & 7;              // (r ^ l) & 7
            const int pu = u ^ (K3 << 1);
            union { unsigned uu[2]; uint2v v2; } o;
            asm("v_cvt_pk_bf16_f32 %0, %1, %2" : "=v"(o.uu[0]) : "v"(f[i][0]), "v"(f[i][1]));
            asm("v_cvt_pk_bf16_f32 %0, %1, %2" : "=v"(o.uu[1]) : "v"(f[i][2]), "v"(f[i][3]));
            *(uint2v*)&Ssh[(R << 6) + (pu << 2)] = o.v2;
        }
    }
    __syncthreads();

#pragma unroll
    for (int bhg = 0; bhg < 2; ++bhg) {
        const int bhb = bhh * 32 + bhg * 16;     // wave's bh base this pass
        float kbreg[4];
#pragma unroll
        for (int j = 0; j < 4; ++j)
            kbreg[j] = kbv[(size_t)(r0 + row4 + j) * 64 + bhb + lrow];
        // ---- T3: c3[ri][j] = t3(l = lh*16+4g+j ... A rows l=lh*16+lrow ----
        float4v c3[16];
#pragma unroll
        for (int ri = 0; ri < 16; ++ri) {
            const int row = lh * 256 + lrow * 16 + ri;   // l = lh*16+lrow, r = ri
            const int key = (ri ^ lrow) & 7;
            short8v a0 = *(const short8v*)&Ssh[row * 64 + ((g ^ key) << 3)];
            short8v a1 = *(const short8v*)&Ssh[row * 64 + (((4 + g) ^ key) << 3)];
            const unsigned short* Bp = k2b + ((size_t)(r0 + ri) * 64 + bhb + lrow) * 64 + g8;
            short8v b0 = *(const short8v*)Bp;
            short8v b1 = *(const short8v*)(Bp + 32);
            float4v acc = {};
            acc = MFMA16(a0, b0, acc);
            acc = MFMA16(a1, b1, acc);
            c3[ri] = acc;
        }
        // ---- T2 in 4 li-groups; JIT dump of matching T3 slice ----
#pragma unroll
        for (int G = 0; G < 4; ++G) {
            if (g == G) {
#pragma unroll
                for (int j = 0; j < 4; ++j) {
                    float4v la{c3[0][j], c3[1][j], c3[2][j], c3[3][j]};
                    float4v lb{c3[4][j], c3[5][j], c3[6][j], c3[7][j]};
                    float4v ha{c3[8][j], c3[9][j], c3[10][j], c3[11][j]};
                    float4v hb{c3[12][j], c3[13][j], c3[14][j], c3[15][j]};
                    *(short8v*)&t3g[w][j][lrow][0] = pack8(la, lb);
                    *(short8v*)&t3g[w][j][lrow][8] = pack8(ha, hb);
                }
            }
            asm volatile("s_waitcnt lgkmcnt(0)" ::: "memory");
#pragma unroll
            for (int lj = 0; lj < 4; ++lj) {
                const int li = (G << 2) + lj;
                const int l = l0 + lh * 16 + li;
                const int row = lh * 256 + li * 16 + lrow;   // r = lrow
                const int key = (li ^ lrow) & 7;
                short8v a0 = *(const short8v*)&Ssh[row * 64 + ((g ^ key) << 3)];
                short8v a1 = *(const short8v*)&Ssh[row * 64 + (((4 + g) ^ key) << 3)];
                const unsigned short* Bp = q2b + ((size_t)l * 64 + bhb + lrow) * 64 + g8;
                short8v b0 = *(const short8v*)Bp;
                short8v b1 = *(const short8v*)(Bp + 32);
                float4v c2 = {};
                c2 = MFMA16(a0, b0, c2);
                c2 = MFMA16(a1, b1, c2);
                short4v t3v = *(const short4v*)&t3g[w][lj][lrow][row4];
                const float qb = qbv[(size_t)l * 64 + bhb + lrow];
                short4v outv;
#pragma unroll
                for (int j = 0; j < 4; ++j)
                    outv[j] = (short)f2b(c2[j] + b2f((unsigned short)t3v[j]) + qb + kbreg[j]);
                *(short4v*)&sb[((size_t)l * 64 + bhb + lrow) * 1024 + r0 + row4] = outv;
            }
        }
    }
}

// ---------------------------------------------------------------------------
// P6 v3: barrier-free flash, 16 l-rows per wave (halved register state ->
// 2x latency-hiding) + s_setprio around MFMA clusters (T5, m191).
// Grid 1024 = 64 bh x 16 segs; block = 4 independent waves, same bh.
// ---------------------------------------------------------------------------
__global__ __launch_bounds__(256, 4) void flash_kernel(
    const unsigned short* __restrict__ qh,  // [64][1024][64] bf16
    const unsigned short* __restrict__ kh,
    const unsigned short* __restrict__ vT,  // [64][64][1024] bf16
    const unsigned short* __restrict__ sb,  // [1024][64][1024] bf16
    const float* __restrict__ mask,         // [4][1024]
    float* __restrict__ scores,             // [64][1024][1024]
    float* __restrict__ ctx) {              // [4][1024][1024]
    __shared__ __align__(16) unsigned short pL[2][4][16][64];  // 16 KB
    const int bid = blockIdx.x;
    const int bh  = (bid & 7) * 8 + ((bid >> 3) & 7);
    const int seg = bid >> 6;                        // 0..15
    const int tid = threadIdx.x, w = tid >> 6, lane = tid & 63;
    const int l0 = ((seg << 2) | w) << 4;            // wave's 16-row l-base
    const int b = bh >> 4, h = bh & 15;
    const int lam = lane & 15, g = lane >> 4, g8 = g << 3, g4 = g << 2;
    const int key = (lam & 7) << 1;                  // 8B-unit XOR key (even)

    short8v qf[2];
#pragma unroll
    for (int ks = 0; ks < 2; ++ks)
        qf[ks] = *(const short8v*)&qh[((size_t)bh * 1024 + l0 + lam) * 64 + ks * 32 + g8];
    const int myl = l0 + lam;
    float mrun = -3e38f, sden = 0.f;
    float4v opv[4] = {};

    for (int rt = 0; rt < 16; ++rt) {
        const int r0 = rt << 6;
        const int pc = rt & 1;
        // --- QK^T swapped: D[r][l], cols = l = lane&15 ---
        float4v sacc[4] = {};
        __builtin_amdgcn_s_setprio(1);
#pragma unroll
        for (int rs = 0; rs < 4; ++rs)
#pragma unroll
            for (int ks = 0; ks < 2; ++ks) {
                short8v kf = *(const short8v*)&kh[((size_t)bh * 1024 + r0 + rs * 16 + lam) * 64 + ks * 32 + g8];
                sacc[rs] = MFMA16(kf, qf[ks], sacc[rs]);
            }
        __builtin_amdgcn_s_setprio(0);
        // --- assemble scores (lane holds r = r0+rs*16+g*4+j for its l) ---
        float s8[4][4];
        float mx = -3e38f;
#pragma unroll
        for (int rs = 0; rs < 4; ++rs) {
            float4v mk = *(const float4v*)&mask[(size_t)b * 1024 + r0 + rs * 16 + g4];
            short4v sbv = *(const short4v*)&sb[((size_t)myl * 64 + bh) * 1024 + r0 + rs * 16 + g4];
            float4v o;
#pragma unroll
            for (int j = 0; j < 4; ++j) {
                const float v = (sacc[rs][j] + b2f((unsigned short)sbv[j])) * 0.125f + mk[j];
                s8[rs][j] = v; o[j] = v;
                mx = fmaxf(mx, v);
            }
            *(float4v*)&scores[((size_t)bh * 1024 + myl) * 1024 + r0 + rs * 16 + g4] = o;
        }
        // --- online softmax: per-l reduce across the 4 g-replicas ---
        {
            float t = mx;
            t = fmaxf(t, __shfl_xor(t, 16));
            t = fmaxf(t, __shfl_xor(t, 32));
            const float mn = fmaxf(mrun, t);
            const float f = __expf(mrun - mn);
            mrun = mn;
            float ps = 0.f;
#pragma unroll
            for (int rs = 0; rs < 4; ++rs)
#pragma unroll
                for (int j = 0; j < 4; ++j) {
                    const float p = __expf(s8[rs][j] - mn);
                    s8[rs][j] = p; ps += p;
                }
            ps += __shfl_xor(ps, 16);
            ps += __shfl_xor(ps, 32);
            sden = sden * f + ps;
#pragma unroll
            for (int dt = 0; dt < 4; ++dt)
#pragma unroll
                for (int j = 0; j < 4; ++j) opv[dt][j] *= f;
        }
        // --- P -> per-wave LDS (bf16, swizzled 8B units; dbuf by rt parity) ---
#pragma unroll
        for (int rs = 0; rs < 4; ++rs) {
            union { unsigned uu[2]; uint2v v2; } o;
            asm("v_cvt_pk_bf16_f32 %0, %1, %2" : "=v"(o.uu[0]) : "v"(s8[rs][0]), "v"(s8[rs][1]));
            asm("v_cvt_pk_bf16_f32 %0, %1, %2" : "=v"(o.uu[1]) : "v"(s8[rs][2]), "v"(s8[rs][3]));
            const int unit = ((rs << 2) | g) ^ key;
            *(uint2v*)&pL[pc][w][lam][unit << 2] = o.v2;
        }
        // --- PV: O^T[d][l], A = vT rows d, B = P cols l ---
#pragma unroll
        for (int ks = 0; ks < 2; ++ks) {
            const int u = (((ks << 3) | (g << 1)) ^ key) << 2;   // u16 elems
            short8v pb = *(const short8v*)&pL[pc][w][lam][u];
            __builtin_amdgcn_s_setprio(1);
#pragma unroll
            for (int dt = 0; dt < 4; ++dt) {
                short8v va = *(const short8v*)&vT[((size_t)bh * 64 + dt * 16 + lam) * 1024 + r0 + ks * 32 + g8];
                opv[dt] = MFMA16(va, pb, opv[dt]);
            }
            __builtin_amdgcn_s_setprio(0);
        }
    }
    // --- epilogue: ctx[b][l][h*64+d] = O^T / s ---
    {
        const float inv = 1.f / sden;
#pragma unroll
        for (int dt = 0; dt < 4; ++dt) {
            float4v o;
#pragma unroll
            for (int j = 0; j < 4; ++j) o[j] = opv[dt][j] * inv;
            *(float4v*)&ctx[((size_t)b * 1024 + myl) * 1024 + h * 64 + dt * 16 + g4] = o;
        }
    }
}

// ---------------------------------------------------------------------------
extern "C" void kernel_launch(void* const* d_in, const int* in_sizes, int n_in,
                              void* d_out, int out_size, void* d_ws, size_t ws_size,
                              hipStream_t stream) {
    (void)in_sizes; (void)n_in; (void)out_size; (void)ws_size;
    const float* hidden = (const float*)d_in[0];
    const float* mask   = (const float*)d_in[1];
    const float* S      = (const float*)d_in[2];
    const float* Wq  = (const float*)d_in[3];  const float* bq  = (const float*)d_in[4];
    const float* Wk  = (const float*)d_in[5];  const float* bk  = (const float*)d_in[6];
    const float* Wv  = (const float*)d_in[7];  const float* bv  = (const float*)d_in[8];
    const float* Wsq = (const float*)d_in[9];  const float* bsq = (const float*)d_in[10];
    const float* Wsk = (const float*)d_in[11]; const float* bsk = (const float*)d_in[12];

    float* ctx    = (float*)d_out;
    float* scores = ctx + (size_t)4 * 1024 * 1024;

    char* ws = (char*)d_ws;
    unsigned short* sbuf = (unsigned short*)ws;                 // [1024][64][1024] bf16, 128 MB
    unsigned short* hb  = (unsigned short*)ws;                  // stage-1 temps alias sbuf
    unsigned short* Wqb = (unsigned short*)(ws + (8u << 20));
    unsigned short* Wkb = (unsigned short*)(ws + (10u << 20));
    unsigned short* Wvb = (unsigned short*)(ws + (12u << 20));
    unsigned short* qh  = (unsigned short*)(ws + (size_t)(128u) * 1024 * 1024);
    unsigned short* kh  = qh  + (size_t)4 * 1024 * 1024;
    unsigned short* vT  = kh  + (size_t)4 * 1024 * 1024;
    unsigned short* q2b = vT  + (size_t)4 * 1024 * 1024;
    unsigned short* k2b = q2b + (size_t)4 * 1024 * 1024;
    float* qbv = (float*)(k2b + (size_t)4 * 1024 * 1024);
    float* kbv = qbv + 65536;

    pack_all<<<3584, 256, 0, stream>>>(hidden, Wq, Wk, Wv, hb, Wqb, Wkb, Wvb);
    qkv_gemm<<<dim3(48, 32), 256, 0, stream>>>(hb, Wqb, Wkb, Wvb, bq, bk, bv, qh);
    headproj<<<1024, 256, 0, stream>>>(qh, Wsq, bsq, q2b, qbv);
    headproj<<<1024, 256, 0, stream>>>(kh, Wsk, bsk, k2b, kbv);
    struct_fused<<<dim3(64, 32), 256, 0, stream>>>(S, q2b, k2b, qbv, kbv, sbuf);
    flash_kernel<<<1024, 256, 0, stream>>>(qh, kh, vT, sbuf, mask, scores, ctx);
}

// Round 14
// 521.044 us; speedup vs baseline: 1.1130x; 1.1130x over previous
//
#include <hip/hip_runtime.h>

typedef __attribute__((ext_vector_type(8))) short short8v;
typedef __attribute__((ext_vector_type(4))) short short4v;
typedef __attribute__((ext_vector_type(4))) float float4v;
typedef __attribute__((ext_vector_type(2))) unsigned int uint2v;

#define MFMA16(a,b,c) __builtin_amdgcn_mfma_f32_16x16x32_bf16(a,b,c,0,0,0)

__device__ __forceinline__ unsigned short f2b(float f) {
    union { float f; unsigned u; } v; v.f = f;
    unsigned r = v.u + 0x7FFFu + ((v.u >> 16) & 1u);
    return (unsigned short)(r >> 16);
}
__device__ __forceinline__ float b2f(unsigned short s) {
    union { unsigned u; float f; } v; v.u = ((unsigned)s) << 16;
    return v.f;
}
// RNE f32x8 -> bf16x8 via v_cvt_pk_bf16_f32 (same rounding as f2b)
__device__ __forceinline__ short8v pack8(float4v a, float4v b) {
    union { unsigned u[4]; short8v s; } o;
    asm("v_cvt_pk_bf16_f32 %0, %1, %2" : "=v"(o.u[0]) : "v"(a[0]), "v"(a[1]));
    asm("v_cvt_pk_bf16_f32 %0, %1, %2" : "=v"(o.u[1]) : "v"(a[2]), "v"(a[3]));
    asm("v_cvt_pk_bf16_f32 %0, %1, %2" : "=v"(o.u[2]) : "v"(b[0]), "v"(b[1]));
    asm("v_cvt_pk_bf16_f32 %0, %1, %2" : "=v"(o.u[3]) : "v"(b[2]), "v"(b[3]));
    return o.s;
}

// ---------------------------------------------------------------------------
// P1: consolidated f32 -> bf16 pack for hidden / Wq / Wk / Wv (one launch).
// ---------------------------------------------------------------------------
__global__ __launch_bounds__(256) void pack_all(
    const float* __restrict__ hidden, const float* __restrict__ Wq,
    const float* __restrict__ Wk, const float* __restrict__ Wv,
    unsigned short* __restrict__ hb, unsigned short* __restrict__ Wqb,
    unsigned short* __restrict__ Wkb, unsigned short* __restrict__ Wvb) {
    const int bid = blockIdx.x;
    const float* in; unsigned short* out; int i;
    if (bid < 2048)      { in = hidden; out = hb;  i = bid * 256 + threadIdx.x; }
    else if (bid < 2560) { in = Wq; out = Wqb; i = (bid - 2048) * 256 + threadIdx.x; }
    else if (bid < 3072) { in = Wk; out = Wkb; i = (bid - 2560) * 256 + threadIdx.x; }
    else                 { in = Wv; out = Wvb; i = (bid - 3072) * 256 + threadIdx.x; }
    float4v a = *(const float4v*)&in[(size_t)i * 8];
    float4v b = *(const float4v*)&in[(size_t)i * 8 + 4];
    *(short8v*)&out[(size_t)i * 8] = pack8(a, b);
}

// ---------------------------------------------------------------------------
// P2 (FUSED): one launch for q, k, v.  grid (48, 32).
// ---------------------------------------------------------------------------
__global__ __launch_bounds__(256) void qkv_gemm(
    const unsigned short* __restrict__ A,     // [4096][1024] bf16
    const unsigned short* __restrict__ Wqb, const unsigned short* __restrict__ Wkb,
    const unsigned short* __restrict__ Wvb,   // each [1024][1024] bf16 [n][k]
    const float* __restrict__ bq, const float* __restrict__ bk,
    const float* __restrict__ bv,
    unsigned short* __restrict__ outq) {      // qh | kh | vT consecutive 4M each
    const int n0g = blockIdx.x * 64;
    const int which = n0g >> 10;
    const int n0 = n0g & 1023;
    const unsigned short* W = (which == 0) ? Wqb : (which == 1) ? Wkb : Wvb;
    const float* bias = (which == 0) ? bq : (which == 1) ? bk : bv;
    unsigned short* out = outq + (size_t)which * 4194304;
    const int vmode = (which == 2);
    const int wave = threadIdx.x >> 6, lane = threadIdx.x & 63;
    const int m0 = blockIdx.y * 128 + wave * 32;
    const int lrow = lane & 15, g8 = (lane >> 4) << 3, row4 = (lane >> 4) << 2;
    float4v acc[2][4] = {};
    const unsigned short* Ap = A + (size_t)(m0 + lrow) * 1024 + g8;
    const unsigned short* Wp = W + (size_t)(n0 + lrow) * 1024 + g8;
#pragma unroll 2
    for (int k0 = 0; k0 < 1024; k0 += 32) {
        short8v a0 = *(const short8v*)(Ap + k0);
        short8v a1 = *(const short8v*)(Ap + 16 * 1024 + k0);
        short8v b0 = *(const short8v*)(Wp + k0);
        short8v b1 = *(const short8v*)(Wp + 16 * 1024 + k0);
        short8v b2 = *(const short8v*)(Wp + 32 * 1024 + k0);
        short8v b3 = *(const short8v*)(Wp + 48 * 1024 + k0);
        acc[0][0] = MFMA16(a0, b0, acc[0][0]); acc[0][1] = MFMA16(a0, b1, acc[0][1]);
        acc[0][2] = MFMA16(a0, b2, acc[0][2]); acc[0][3] = MFMA16(a0, b3, acc[0][3]);
        acc[1][0] = MFMA16(a1, b0, acc[1][0]); acc[1][1] = MFMA16(a1, b1, acc[1][1]);
        acc[1][2] = MFMA16(a1, b2, acc[1][2]); acc[1][3] = MFMA16(a1, b3, acc[1][3]);
    }
#pragma unroll
    for (int nt = 0; nt < 4; ++nt) {
        const int n = n0 + nt * 16 + lrow;           // C col = lane&15
        const float bz = bias[n];
        const int h = n >> 6, d = n & 63;
#pragma unroll
        for (int mt = 0; mt < 2; ++mt) {
            const int mb = m0 + mt * 16 + row4;      // C row = (lane>>4)*4 + j
            if (vmode == 0) {
#pragma unroll
                for (int j = 0; j < 4; ++j) {
                    const int m = mb + j;
                    const int b = m >> 10, l = m & 1023;
                    out[(((size_t)(b * 16 + h) << 10) + l) * 64 + d] = f2b(acc[mt][nt][j] + bz);
                }
            } else {
                const int b = mb >> 10, r = mb & 1023;
                short4v pk;
#pragma unroll
                for (int j = 0; j < 4; ++j) pk[j] = (short)f2b(acc[mt][nt][j] + bz);
                *(short4v*)&out[((((size_t)(b * 16 + h)) << 6) + d) * 1024 + r] = pk;
            }
        }
    }
}

// ---------------------------------------------------------------------------
// P3 (FUSED): headproj for q AND k in one launch; grid 2048.
// blocks 0..1023: q -> q2b/qbv; 1024..2047: k -> k2b/kbv.
// ---------------------------------------------------------------------------
__global__ __launch_bounds__(256) void headproj_both(
    const unsigned short* __restrict__ qh,  // [64][1024][64] bf16
    const unsigned short* __restrict__ kh,
    const float* __restrict__ Wsq, const float* __restrict__ bsq,
    const float* __restrict__ Wsk, const float* __restrict__ bsk,
    unsigned short* __restrict__ q2b, float* __restrict__ qbv,
    unsigned short* __restrict__ k2b, float* __restrict__ kbv) {
    const int which = blockIdx.x >> 10;
    const int l = blockIdx.x & 1023;
    const unsigned short* xh = which ? kh : qh;
    const float* Wsx = which ? Wsk : Wsq;
    const float* bsx = which ? bsk : bsq;
    unsigned short* x2b = which ? k2b : q2b;
    float* xbv = which ? kbv : qbv;
    __shared__ __align__(16) float Ws[64 * 64];
    __shared__ float bs[64];
    __shared__ __align__(16) unsigned short Xl[64 * 64];
    const int tid = threadIdx.x;
#pragma unroll
    for (int i = 0; i < 4; ++i)
        *(float4v*)&Ws[tid * 4 + i * 1024] = *(const float4v*)&Wsx[tid * 4 + i * 1024];
    if (tid < 64) bs[tid] = bsx[tid];
    {
        const int bhh = tid >> 2, dq = (tid & 3) * 16;
        const unsigned short* src = &xh[((size_t)bhh * 1024 + l) * 64 + dq];
        *(short8v*)&Xl[bhh * 64 + dq] = *(const short8v*)src;
        *(short8v*)&Xl[bhh * 64 + dq + 8] = *(const short8v*)(src + 8);
    }
    __syncthreads();
    const int bh = tid >> 2, e0 = (tid & 3) * 16;
    float acc[16] = {};
    float bacc = 0.f;
    for (int d = 0; d < 64; ++d) {
        const float xd = b2f(Xl[bh * 64 + d]);
        bacc += xd * bs[d];
        const float* wr = &Ws[d * 64 + e0];
#pragma unroll
        for (int e = 0; e < 16; e += 4) {
            float4v w = *(const float4v*)&wr[e];
            acc[e] += xd * w[0]; acc[e + 1] += xd * w[1];
            acc[e + 2] += xd * w[2]; acc[e + 3] += xd * w[3];
        }
    }
    short8v p0, p1;
#pragma unroll
    for (int e = 0; e < 8; ++e) { p0[e] = (short)f2b(acc[e]); p1[e] = (short)f2b(acc[e + 8]); }
    unsigned short* dst = &x2b[((size_t)l * 64 + bh) * 64 + e0];
    *(short8v*)dst = p0; *(short8v*)(dst + 8) = p1;
    if ((tid & 3) == 0) xbv[l * 64 + bh] = bacc;
}

// ---------------------------------------------------------------------------
// P4 v10 (measured best: R11, ~196-201 us): reg-staged swizzled bf16 S tile,
// 40 KB LDS, 4 blocks/CU, XCD-chunked 1-D remap (xcd = n&7 owns r-tiles
// [8x,8x+8) for all l).
// ---------------------------------------------------------------------------
__global__ __launch_bounds__(256, 4) void struct_fused(
    const float* __restrict__ S,              // [1024][1024][64] f32
    const unsigned short* __restrict__ q2b,   // [1024][64][64] bf16
    const unsigned short* __restrict__ k2b,   // [1024][64][64] bf16
    const float* __restrict__ qbv,            // [1024][64]
    const float* __restrict__ kbv,            // [1024][64]
    unsigned short* __restrict__ sb) {        // [1024][64][1024] bf16
    __shared__ __align__(16) unsigned short Ssh[256 * 64];       // 32 KB
    __shared__ __align__(16) unsigned short t3g[4][4][16][16];   // 8 KB
    const int tid = threadIdx.x;
    const int w = tid >> 6, lane = tid & 63;
    const int lrow = lane & 15, g = lane >> 4;
    const int g8 = g << 3, row4 = g << 2;
    const int w16 = w << 4;
    const int n = blockIdx.x;
    const int xcd = n & 7;
    const int idx = n >> 3;                  // 0..511
    const int rt = (xcd << 3) | (idx & 7);   // r-tile 0..63
    const int lt = idx >> 3;                 // l-tile 0..63
    const int r0 = rt << 4, l0 = lt << 4;

    {
        const int u = tid & 15, roff = tid >> 4;
        const float* gp = S + ((size_t)l0 * 1024 + r0 + roff) * 64 + u * 4;
        float4v f[16];
#pragma unroll
        for (int i = 0; i < 16; ++i)
            f[i] = *(const float4v*)(gp + (size_t)i * 65536);   // +l -> +1024*64
#pragma unroll
        for (int i = 0; i < 16; ++i) {
            const int R = (i << 4) + roff;
            const int K3 = (roff ^ i) & 7;            // (R ^ R>>4) & 7
            const int pu = u ^ (K3 << 1);
            union { unsigned uu[2]; uint2v v2; } o;
            asm("v_cvt_pk_bf16_f32 %0, %1, %2" : "=v"(o.uu[0]) : "v"(f[i][0]), "v"(f[i][1]));
            asm("v_cvt_pk_bf16_f32 %0, %1, %2" : "=v"(o.uu[1]) : "v"(f[i][2]), "v"(f[i][3]));
            *(uint2v*)&Ssh[(R << 6) + (pu << 2)] = o.v2;
        }
    }
    float kbreg[4];
#pragma unroll
    for (int j = 0; j < 4; ++j)
        kbreg[j] = kbv[(size_t)(r0 + row4 + j) * 64 + w16 + lrow];
    __syncthreads();

    float4v c3[16];
#pragma unroll
    for (int ri = 0; ri < 16; ++ri) {
        const int row = lrow * 16 + ri;
        const int key = (lrow ^ ri) & 7;
        short8v a0 = *(const short8v*)&Ssh[row * 64 + ((g ^ key) << 3)];
        short8v a1 = *(const short8v*)&Ssh[row * 64 + (((4 + g) ^ key) << 3)];
        const unsigned short* Bp = k2b + ((size_t)(r0 + ri) * 64 + w16 + lrow) * 64 + g8;
        short8v b0 = *(const short8v*)Bp;
        short8v b1 = *(const short8v*)(Bp + 32);
        float4v acc = {};
        acc = MFMA16(a0, b0, acc);
        acc = MFMA16(a1, b1, acc);
        c3[ri] = acc;
    }

#pragma unroll
    for (int G = 0; G < 4; ++G) {
        if (g == G) {
#pragma unroll
            for (int j = 0; j < 4; ++j) {
                float4v la{c3[0][j], c3[1][j], c3[2][j], c3[3][j]};
                float4v lb{c3[4][j], c3[5][j], c3[6][j], c3[7][j]};
                float4v ha{c3[8][j], c3[9][j], c3[10][j], c3[11][j]};
                float4v hb{c3[12][j], c3[13][j], c3[14][j], c3[15][j]};
                *(short8v*)&t3g[w][j][lrow][0] = pack8(la, lb);
                *(short8v*)&t3g[w][j][lrow][8] = pack8(ha, hb);
            }
        }
        asm volatile("s_waitcnt lgkmcnt(0)" ::: "memory");
#pragma unroll
        for (int lj = 0; lj < 4; ++lj) {
            const int li = (G << 2) + lj;
            const int row = li * 16 + lrow;
            const int key = (li ^ lrow) & 7;
            short8v a0 = *(const short8v*)&Ssh[row * 64 + ((g ^ key) << 3)];
            short8v a1 = *(const short8v*)&Ssh[row * 64 + (((4 + g) ^ key) << 3)];
            const unsigned short* Bp = q2b + ((size_t)(l0 + li) * 64 + w16 + lrow) * 64 + g8;
            short8v b0 = *(const short8v*)Bp;
            short8v b1 = *(const short8v*)(Bp + 32);
            float4v c2 = {};
            c2 = MFMA16(a0, b0, c2);
            c2 = MFMA16(a1, b1, c2);
            short4v t3v = *(const short4v*)&t3g[w][lj][lrow][row4];
            const float qb = qbv[(size_t)(l0 + li) * 64 + w16 + lrow];
            short4v outv;
#pragma unroll
            for (int j = 0; j < 4; ++j)
                outv[j] = (short)f2b(c2[j] + b2f((unsigned short)t3v[j]) + qb + kbreg[j]);
            *(short4v*)&sb[((size_t)(l0 + li) * 64 + w16 + lrow) * 1024 + r0 + row4] = outv;
        }
    }
}

// ---------------------------------------------------------------------------
// P6 v2 (R12, co-measured neutral-or-better): barrier-free flash, swapped
// QK^T, 32 l-rows/wave, per-wave dbuf LDS transpose. Grid 512.
// ---------------------------------------------------------------------------
__global__ __launch_bounds__(256) void flash_kernel(
    const unsigned short* __restrict__ qh,  // [64][1024][64] bf16
    const unsigned short* __restrict__ kh,
    const unsigned short* __restrict__ vT,  // [64][64][1024] bf16
    const unsigned short* __restrict__ sb,  // [1024][64][1024] bf16
    const float* __restrict__ mask,         // [4][1024]
    float* __restrict__ scores,             // [64][1024][1024]
    float* __restrict__ ctx) {              // [4][1024][1024]
    __shared__ __align__(16) unsigned short pL[2][4][2][16][64];  // 32 KB
    const int bid = blockIdx.x;
    const int bh  = (bid & 7) * 8 + ((bid >> 3) & 7);
    const int seg = bid >> 6;                        // 0..7
    const int tid = threadIdx.x, w = tid >> 6, lane = tid & 63;
    const int l0 = ((seg << 2) | w) << 5;            // wave's 32-row l-base
    const int b = bh >> 4, h = bh & 15;
    const int lam = lane & 15, g = lane >> 4, g8 = g << 3, g4 = g << 2;
    const int key = (lam & 7) << 1;                  // 8B-unit XOR key (even)

    short8v qf[2][2];
#pragma unroll
    for (int mt = 0; mt < 2; ++mt)
#pragma unroll
        for (int ks = 0; ks < 2; ++ks)
            qf[mt][ks] = *(const short8v*)&qh[((size_t)bh * 1024 + l0 + mt * 16 + lam) * 64 + ks * 32 + g8];
    const int myl[2] = { l0 + lam, l0 + 16 + lam };
    float mrun[2] = { -3e38f, -3e38f }, sden[2] = { 0.f, 0.f };
    float4v opv[2][4] = {};

    for (int rt = 0; rt < 16; ++rt) {
        const int r0 = rt << 6;
        const int pc = rt & 1;
        float4v sacc[2][4] = {};
#pragma unroll
        for (int rs = 0; rs < 4; ++rs)
#pragma unroll
            for (int ks = 0; ks < 2; ++ks) {
                short8v kf = *(const short8v*)&kh[((size_t)bh * 1024 + r0 + rs * 16 + lam) * 64 + ks * 32 + g8];
                sacc[0][rs] = MFMA16(kf, qf[0][ks], sacc[0][rs]);
                sacc[1][rs] = MFMA16(kf, qf[1][ks], sacc[1][rs]);
            }
        float s8[2][4][4];
        float mx[2] = { -3e38f, -3e38f };
#pragma unroll
        for (int rs = 0; rs < 4; ++rs) {
            float4v mk = *(const float4v*)&mask[(size_t)b * 1024 + r0 + rs * 16 + g4];
#pragma unroll
            for (int mt = 0; mt < 2; ++mt) {
                short4v sbv = *(const short4v*)&sb[((size_t)myl[mt] * 64 + bh) * 1024 + r0 + rs * 16 + g4];
                float4v o;
#pragma unroll
                for (int j = 0; j < 4; ++j) {
                    const float v = (sacc[mt][rs][j] + b2f((unsigned short)sbv[j])) * 0.125f + mk[j];
                    s8[mt][rs][j] = v; o[j] = v;
                    mx[mt] = fmaxf(mx[mt], v);
                }
                *(float4v*)&scores[((size_t)bh * 1024 + myl[mt]) * 1024 + r0 + rs * 16 + g4] = o;
            }
        }
#pragma unroll
        for (int mt = 0; mt < 2; ++mt) {
            float t = mx[mt];
            t = fmaxf(t, __shfl_xor(t, 16));
            t = fmaxf(t, __shfl_xor(t, 32));
            const float mn = fmaxf(mrun[mt], t);
            const float f = __expf(mrun[mt] - mn);
            mrun[mt] = mn;
            float ps = 0.f;
#pragma unroll
            for (int rs = 0; rs < 4; ++rs)
#pragma unroll
                for (int j = 0; j < 4; ++j) {
                    const float p = __expf(s8[mt][rs][j] - mn);
                    s8[mt][rs][j] = p; ps += p;
                }
            ps += __shfl_xor(ps, 16);
            ps += __shfl_xor(ps, 32);
            sden[mt] = sden[mt] * f + ps;
#pragma unroll
            for (int dt = 0; dt < 4; ++dt)
#pragma unroll
                for (int j = 0; j < 4; ++j) opv[mt][dt][j] *= f;
        }
#pragma unroll
        for (int mt = 0; mt < 2; ++mt)
#pragma unroll
            for (int rs = 0; rs < 4; ++rs) {
                union { unsigned uu[2]; uint2v v2; } o;
                asm("v_cvt_pk_bf16_f32 %0, %1, %2" : "=v"(o.uu[0]) : "v"(s8[mt][rs][0]), "v"(s8[mt][rs][1]));
                asm("v_cvt_pk_bf16_f32 %0, %1, %2" : "=v"(o.uu[1]) : "v"(s8[mt][rs][2]), "v"(s8[mt][rs][3]));
                const int unit = ((rs << 2) | g) ^ key;
                *(uint2v*)&pL[pc][w][mt][lam][unit << 2] = o.v2;
            }
#pragma unroll
        for (int ks = 0; ks < 2; ++ks) {
            const int u = (((ks << 3) | (g << 1)) ^ key) << 2;   // u16 elems
            short8v pb0 = *(const short8v*)&pL[pc][w][0][lam][u];
            short8v pb1 = *(const short8v*)&pL[pc][w][1][lam][u];
#pragma unroll
            for (int dt = 0; dt < 4; ++dt) {
                short8v va = *(const short8v*)&vT[((size_t)bh * 64 + dt * 16 + lam) * 1024 + r0 + ks * 32 + g8];
                opv[0][dt] = MFMA16(va, pb0, opv[0][dt]);
                opv[1][dt] = MFMA16(va, pb1, opv[1][dt]);
            }
        }
    }
#pragma unroll
    for (int mt = 0; mt < 2; ++mt) {
        const float inv = 1.f / sden[mt];
#pragma unroll
        for (int dt = 0; dt < 4; ++dt) {
            float4v o;
#pragma unroll
            for (int j = 0; j < 4; ++j) o[j] = opv[mt][dt][j] * inv;
            *(float4v*)&ctx[((size_t)b * 1024 + myl[mt]) * 1024 + h * 64 + dt * 16 + g4] = o;
        }
    }
}

// ---------------------------------------------------------------------------
extern "C" void kernel_launch(void* const* d_in, const int* in_sizes, int n_in,
                              void* d_out, int out_size, void* d_ws, size_t ws_size,
                              hipStream_t stream) {
    (void)in_sizes; (void)n_in; (void)out_size; (void)ws_size;
    const float* hidden = (const float*)d_in[0];
    const float* mask   = (const float*)d_in[1];
    const float* S      = (const float*)d_in[2];
    const float* Wq  = (const float*)d_in[3];  const float* bq  = (const float*)d_in[4];
    const float* Wk  = (const float*)d_in[5];  const float* bk  = (const float*)d_in[6];
    const float* Wv  = (const float*)d_in[7];  const float* bv  = (const float*)d_in[8];
    const float* Wsq = (const float*)d_in[9];  const float* bsq = (const float*)d_in[10];
    const float* Wsk = (const float*)d_in[11]; const float* bsk = (const float*)d_in[12];

    float* ctx    = (float*)d_out;
    float* scores = ctx + (size_t)4 * 1024 * 1024;

    char* ws = (char*)d_ws;
    unsigned short* sbuf = (unsigned short*)ws;                 // [1024][64][1024] bf16, 128 MB
    unsigned short* hb  = (unsigned short*)ws;                  // stage-1 temps alias sbuf
    unsigned short* Wqb = (unsigned short*)(ws + (8u << 20));
    unsigned short* Wkb = (unsigned short*)(ws + (10u << 20));
    unsigned short* Wvb = (unsigned short*)(ws + (12u << 20));
    unsigned short* qh  = (unsigned short*)(ws + (size_t)(128u) * 1024 * 1024);
    unsigned short* kh  = qh  + (size_t)4 * 1024 * 1024;
    unsigned short* vT  = kh  + (size_t)4 * 1024 * 1024;
    unsigned short* q2b = vT  + (size_t)4 * 1024 * 1024;
    unsigned short* k2b = q2b + (size_t)4 * 1024 * 1024;
    float* qbv = (float*)(k2b + (size_t)4 * 1024 * 1024);
    float* kbv = qbv + 65536;

    pack_all<<<3584, 256, 0, stream>>>(hidden, Wq, Wk, Wv, hb, Wqb, Wkb, Wvb);
    qkv_gemm<<<dim3(48, 32), 256, 0, stream>>>(hb, Wqb, Wkb, Wvb, bq, bk, bv, qh);
    headproj_both<<<2048, 256, 0, stream>>>(qh, kh, Wsq, bsq, Wsk, bsk, q2b, qbv, k2b, kbv);
    struct_fused<<<4096, 256, 0, stream>>>(S, q2b, k2b, qbv, kbv, sbuf);
    flash_kernel<<<512, 256, 0, stream>>>(qh, kh, vT, sbuf, mask, scores, ctx);
}